// Round 9
// baseline (195.877 us; speedup 1.0000x reference)
//
#include <hip/hip_runtime.h>
#include <hip/hip_cooperative_groups.h>

namespace cg = cooperative_groups;

// NALU B=1024, I=512, O=512 — ONE cooperative dispatch, fp16 MFMA 16x16x32.
//   w1 = tanh(w_hat)*sigmoid(m_hat); a = x@w1; s = log(max(|x|,eps))@w1
//   m1 = exp(min(s,20)); out = g1*a + (1-g1)*m1*clip(ms,-1,1)
// s ~ N(-143,11^2) => m1 underflows to 0; guarded exactly: any s > -80
// takes a cold path computing the true sign-product from wh/mh.
//
// Structure (from R1-R8 budget decomposition):
//  - per-block w1 staging is the fused-kernel poison (R4/R6/R8: ~25-30 us of
//    strided reads + x32-redundant transcendentals) -> keep ONE-SHOT parallel
//    prep, but replace the kernel boundary with cg::grid.sync() so the whole
//    thing is a single graph node (R4 datum: single-dispatch gap ~2.4 us).
//  - phase 2 stages all fragments into LDS via __builtin_amdgcn_global_load_lds
//    (width 16, m97-proven): 16 async 1KB stages/wave, one barrier, then a
//    pure ds_read_b128 + MFMA loop. 512 blocks co-resident (2/CU, 64KB LDS),
//    2 tiles per block, B-frags staged once.
// Frag layouts (learn_hip-verified): A[m=lane&15][k=(lane>>4)*8+j],
// B[k=(lane>>4)*8+j][n=lane&15], D[m=(lane>>4)*4+reg][n=lane&15].

#define O_N 512
#define I_N 512
#define B_N 1024

typedef _Float16 f16;
typedef _Float16 f16x8 __attribute__((ext_vector_type(8)));
typedef float f32x4 __attribute__((ext_vector_type(4)));

__device__ __forceinline__ float fast_sigmoid(float v) {
    return 1.0f / (1.0f + __expf(-v));
}
__device__ __forceinline__ float fast_tanh(float v) {
    return 1.0f - 2.0f / (1.0f + __expf(2.0f * v));   // exact at both tails
}

// async global->LDS, 16B per lane; LDS dst is wave-uniform base + lane*16
__device__ __forceinline__ void async16(const f16x8* gsrc, f16x8* ldst) {
    __builtin_amdgcn_global_load_lds(
        (const __attribute__((address_space(1))) unsigned int*)gsrc,
        (__attribute__((address_space(3))) unsigned int*)ldst,
        16, 0, 0);
}

__global__ __launch_bounds__(256, 2) void nalu_coop_kernel(
        const float* __restrict__ x, const float* __restrict__ wh,
        const float* __restrict__ mh, const float* __restrict__ g,
        float* __restrict__ out, f16x8* __restrict__ apx,
        f16x8* __restrict__ apl, f16x8* __restrict__ bp) {
    __shared__ f16x8 stage[4][16][64];   // 64 KB: 0=Ax, 1=Al, 2=B(ns0), 3=B(ns1)
    __shared__ float scs[2][16][17];     // 2.2 KB s-result handoff

    const int tid  = threadIdx.x;
    const int lane = tid & 63;
    const int w    = tid >> 6;
    const int blk  = blockIdx.x;

    // ================= phase 1: build frag arrays (R5-prep, proven) =========
    if (blk < 128) {
        // B-prep: w1 tile 32k x 64n, coalesced reads -> LDS transpose -> frags
        f16* lt = (f16*)&stage[0][0][0];    // 32 x 72 overlay (4.6 KB)
        const int kb = blk >> 3;            // 0..15
        const int nb = blk & 7;             // 0..7
        const int r  = tid >> 3;
        const int c0 = (tid & 7) * 8;
        const int base = (kb * 32 + r) * O_N + nb * 64 + c0;
        const float4* w4 = (const float4*)(wh + base);
        const float4* m4 = (const float4*)(mh + base);
        const float4 wa = w4[0], wb = w4[1], ma = m4[0], mb = m4[1];
        f16x8 row;
        row[0] = (f16)(fast_tanh(wa.x) * fast_sigmoid(ma.x));
        row[1] = (f16)(fast_tanh(wa.y) * fast_sigmoid(ma.y));
        row[2] = (f16)(fast_tanh(wa.z) * fast_sigmoid(ma.z));
        row[3] = (f16)(fast_tanh(wa.w) * fast_sigmoid(ma.w));
        row[4] = (f16)(fast_tanh(wb.x) * fast_sigmoid(mb.x));
        row[5] = (f16)(fast_tanh(wb.y) * fast_sigmoid(mb.y));
        row[6] = (f16)(fast_tanh(wb.z) * fast_sigmoid(mb.z));
        row[7] = (f16)(fast_tanh(wb.w) * fast_sigmoid(mb.w));
        *(f16x8*)&lt[r * 72 + c0] = row;
        __syncthreads();
        const int fl  = tid & 63;
        const int tnl = tid >> 6;
        const int nl  = tnl * 16 + (fl & 15);
        const int k0  = (fl >> 4) * 8;
        f16x8 bf;
#pragma unroll
        for (int j = 0; j < 8; ++j) bf[j] = lt[(k0 + j) * 72 + nl];
        bp[(nb * 4 + tnl) * 1024 + kb * 64 + fl] = bf;
        __syncthreads();                    // stage[] reused in phase 2
    } else if (blk < 384) {
        // A-prep: x rows are k-contiguous => direct frag-order float4 reads
        const int t  = (blk - 128) * 256 + tid;
        const int fl = t & 63;
        const int tk = (t >> 6) & 15;
        const int tm = t >> 10;             // 0..63
        const int m  = tm * 16 + (fl & 15);
        const int k0 = tk * 32 + (fl >> 4) * 8;
        const float4* x4 = (const float4*)(x + m * I_N + k0);
        const float4 q0 = x4[0], q1 = x4[1];
        const float vx[8] = {q0.x, q0.y, q0.z, q0.w, q1.x, q1.y, q1.z, q1.w};
        f16x8 fx, fv;
#pragma unroll
        for (int j = 0; j < 8; ++j) {
            fx[j] = (f16)vx[j];
            fv[j] = (f16)__logf(fmaxf(fabsf(vx[j]), 1e-7f));
        }
        apx[t] = fx;
        apl[t] = fv;
    }
    __threadfence();
    cg::this_grid().sync();

    // ================= phase 2: 2 tiles of 16b x 32o per block ==============
    const int bx = blk & 15;                // o-block: o0 = bx*32
    const int st = w & 1;                   // 0: a-stream (x), 1: s-stream (log)
    const int ns = w >> 1;                  // n-subtile

    for (int rep = 0; rep < 2; ++rep) {
        const int by = (blk >> 4) + rep * 32;   // b-tile 0..63

        // stage: wave w fills region w (A restaged per rep; B once)
        if (w < 2) {
            const f16x8* src = (w ? apl : apx) + by * 1024;
#pragma unroll
            for (int i = 0; i < 16; ++i)
                async16(src + i * 64 + lane, &stage[w][i][0]);
        } else if (rep == 0) {
            const f16x8* src = bp + (2 * bx + (w - 2)) * 1024;
#pragma unroll
            for (int i = 0; i < 16; ++i)
                async16(src + i * 64 + lane, &stage[w][i][0]);
        }
        __syncthreads();                    // drains vmcnt: stages complete

        f32x4 acc = {0.f, 0.f, 0.f, 0.f};
#pragma unroll
        for (int tk = 0; tk < 16; ++tk)
            acc = __builtin_amdgcn_mfma_f32_16x16x32_f16(
                stage[st][tk][lane], stage[2 + ns][tk][lane], acc, 0, 0, 0);
        __syncthreads();                    // all LDS reads done (A reuse next rep)

        // epilogue: D[m=(lane>>4)*4+r][n=lane&15]; s-wave -> a-wave via scs
        const int col = lane & 15;
        const int rq  = (lane >> 4) * 4;
        if (st) {
#pragma unroll
            for (int r = 0; r < 4; ++r) scs[ns][rq + r][col] = acc[r];
        }
        __syncthreads();
        if (!st) {
            const int o  = bx * 32 + ns * 16 + col;
            const int b0 = by * 16;
            const float g1  = fast_sigmoid(g[o]);
            const float omg = 1.0f - g1;
#pragma unroll
            for (int r = 0; r < 4; ++r) {
                const int b = b0 + rq + r;
                const float sv = scs[ns][rq + r][col];
                const float m1 = __expf(fminf(sv, 20.0f));
                float msv = 1.0f;
                if (sv > -80.0f) {          // cold path (expected never): exact ms
                    float p = 1.0f;
                    for (int i = 0; i < I_N; ++i) {
                        // ws_oi[o][i] = |w1.flat[o*I+i]| = |w1[row=o][col=i]|
                        const float wv = fabsf(fast_tanh(wh[o * I_N + i]) *
                                               fast_sigmoid(mh[o * I_N + i]));
                        const float xv = x[b * I_N + i];
                        const float sg = (xv > 0.f) ? 1.f : ((xv < 0.f) ? -1.f : 0.f);
                        p *= sg * wv + (1.0f - wv);
                    }
                    msv = fminf(fmaxf(p, -1.0f), 1.0f);
                }
                out[b * O_N + o] = g1 * acc[r] + omg * m1 * msv;
            }
        }
    }
}

extern "C" void kernel_launch(void* const* d_in, const int* in_sizes, int n_in,
                              void* d_out, int out_size, void* d_ws, size_t ws_size,
                              hipStream_t stream) {
    const float* x  = (const float*)d_in[0];   // [B, I]
    const float* wh = (const float*)d_in[1];   // [I, O]
    const float* mh = (const float*)d_in[2];   // [I, O]
    const float* g  = (const float*)d_in[3];   // [O]
    float* out = (float*)d_out;                // [B, O] fp32

    char* ws = (char*)d_ws;
    f16x8* apx = (f16x8*)ws;                   // 1 MB   A frags (x)
    f16x8* apl = (f16x8*)(ws + (1u << 20));    // 1 MB   A frags (log|x|)
    f16x8* bp  = (f16x8*)(ws + (2u << 20));    // 512 KB B frags (w1)

    void* args[] = {(void*)&x, (void*)&wh, (void*)&mh, (void*)&g,
                    (void*)&out, (void*)&apx, (void*)&apl, (void*)&bp};
    // 512 blocks = 2/CU co-resident (LDS 66 KB) — grid-wide sync valid
    hipLaunchCooperativeKernel((void*)nalu_coop_kernel, dim3(512), dim3(256),
                               args, 0, stream);
}

// Round 10
// 74.623 us; speedup vs baseline: 2.6249x; 2.6249x over previous
//
#include <hip/hip_runtime.h>

// NALU B=1024, I=512, O=512 — two dispatches (B-prep + main), fp16 MFMA.
//   w1 = tanh(w_hat)*sigmoid(m_hat); a = x@w1; s = log(max(|x|,eps))@w1
//   m1 = exp(min(s,20)); out = g1*a + (1-g1)*m1*clip(ms,-1,1)
// s ~ N(-143,11^2) => m1 underflows to 0; guarded exactly: any s > -80
// takes a cold path computing the true sign-product from wh/mh.
//
// R10 vs R5: A-prep eliminated entirely. MFMA A-frags are k-contiguous in x
// (A[m=lane&15][k=(lane>>4)*8+j] = two float4s of one x row), so main reads
// x straight from global and computes log|x| in-register (R8-proven loop).
// Prep shrinks to the R5-proven B-branch only (128 blocks): w1 transcendicals
// once, coalesced, LDS-transposed, frag-ordered to ws. Main is LDS-free:
// per tk, 2x global_load_dwordx4 (x row) + 1x dwordx4 (B frag) + 2 MFMA.
// Frag layouts (learn_hip-verified): A[m=lane&15][k=(lane>>4)*8+j],
// B[k=(lane>>4)*8+j][n=lane&15], D[m=(lane>>4)*4+reg][n=lane&15].

#define O_N 512
#define I_N 512
#define B_N 1024

typedef _Float16 f16;
typedef _Float16 f16x8 __attribute__((ext_vector_type(8)));
typedef float f32x4 __attribute__((ext_vector_type(4)));

__device__ __forceinline__ float fast_sigmoid(float v) {
    return 1.0f / (1.0f + __expf(-v));
}
__device__ __forceinline__ float fast_tanh(float v) {
    return 1.0f - 2.0f / (1.0f + __expf(2.0f * v));   // exact at both tails
}

// ---- B-prep (R5-proven branch, standalone): 128 blocks, one 32k x 64n tile each
__global__ __launch_bounds__(256) void prep_b_kernel(const float* __restrict__ wh,
                                                     const float* __restrict__ mh,
                                                     f16x8* __restrict__ bp) {
    __shared__ f16 lt[32][72];          // w1 tile [k][n], 72 to de-conflict
    const int tid = threadIdx.x;
    const int kb = blockIdx.x >> 3;     // 0..15  (k-tile of 32)
    const int nb = blockIdx.x & 7;      // 0..7   (n-tile of 64)
    const int r  = tid >> 3;
    const int c0 = (tid & 7) * 8;
    const int base = (kb * 32 + r) * O_N + nb * 64 + c0;
    const float4* w4 = (const float4*)(wh + base);
    const float4* m4 = (const float4*)(mh + base);
    const float4 wa = w4[0], wb = w4[1], ma = m4[0], mb = m4[1];
    f16x8 row;
    row[0] = (f16)(fast_tanh(wa.x) * fast_sigmoid(ma.x));
    row[1] = (f16)(fast_tanh(wa.y) * fast_sigmoid(ma.y));
    row[2] = (f16)(fast_tanh(wa.z) * fast_sigmoid(ma.z));
    row[3] = (f16)(fast_tanh(wa.w) * fast_sigmoid(ma.w));
    row[4] = (f16)(fast_tanh(wb.x) * fast_sigmoid(mb.x));
    row[5] = (f16)(fast_tanh(wb.y) * fast_sigmoid(mb.y));
    row[6] = (f16)(fast_tanh(wb.z) * fast_sigmoid(mb.z));
    row[7] = (f16)(fast_tanh(wb.w) * fast_sigmoid(mb.w));
    *(f16x8*)&lt[r][c0] = row;          // aligned ds_write_b128
    __syncthreads();
    const int fl  = tid & 63;
    const int tnl = tid >> 6;           // 0..3 local n-subtile
    const int nl  = tnl * 16 + (fl & 15);
    const int k0  = (fl >> 4) * 8;
    f16x8 bf;
#pragma unroll
    for (int j = 0; j < 8; ++j) bf[j] = lt[k0 + j][nl];
    bp[(nb * 4 + tnl) * 1024 + kb * 64 + fl] = bf;   // coalesced 16B store
}

// ---- main: grid (16,32) = 512 blocks, 4 waves; block 32b x 32o, wave 16x16.
// LDS-free: A from x directly (log in-register), B frags from bp (L2-hot).
__global__ __launch_bounds__(256, 4) void nalu_main_kernel(const f16x8* __restrict__ bp,
                                                           const float* __restrict__ x,
                                                           const float* __restrict__ g,
                                                           const float* __restrict__ wh,
                                                           const float* __restrict__ mh,
                                                           float* __restrict__ out) {
    const int lane = threadIdx.x & 63;
    const int w    = threadIdx.x >> 6;
    const int b0   = blockIdx.y * 32 + (w & 1) * 16;
    const int o0   = blockIdx.x * 32 + (w >> 1) * 16;
    const int tn   = o0 >> 4;

    const int m  = b0 + (lane & 15);
    const int k0 = (lane >> 4) * 8;
    const float* px = x + m * I_N + k0;
    const f16x8* pb = bp + tn * 1024 + lane;

    f32x4 ca = {0.f, 0.f, 0.f, 0.f}, cs = ca;

#pragma unroll 4
    for (int tk = 0; tk < 16; ++tk) {
        const float4 q0 = *(const float4*)(px + tk * 32);
        const float4 q1 = *(const float4*)(px + tk * 32 + 4);
        const f16x8 bf = pb[tk * 64];
        const float vx[8] = {q0.x, q0.y, q0.z, q0.w, q1.x, q1.y, q1.z, q1.w};
        f16x8 fx, fv;
#pragma unroll
        for (int j = 0; j < 8; ++j) {
            fx[j] = (f16)vx[j];
            fv[j] = (f16)__logf(fmaxf(fabsf(vx[j]), 1e-7f));
        }
        ca = __builtin_amdgcn_mfma_f32_16x16x32_f16(fx, bf, ca, 0, 0, 0);
        cs = __builtin_amdgcn_mfma_f32_16x16x32_f16(fv, bf, cs, 0, 0, 0);
    }

    // epilogue: D[m=(lane>>4)*4+r][n=lane&15]
    const int col = lane & 15;
    const int rq  = (lane >> 4) * 4;
    const int o   = o0 + col;
    const float g1  = fast_sigmoid(g[o]);
    const float omg = 1.0f - g1;
#pragma unroll
    for (int r = 0; r < 4; ++r) {
        const int b = b0 + rq + r;
        const float sv = cs[r];
        const float m1 = __expf(fminf(sv, 20.0f));
        float msv = 1.0f;
        if (sv > -80.0f) {                  // cold path (expected never): exact ms
            float p = 1.0f;
            for (int i = 0; i < I_N; ++i) {
                // ws_oi[o][i] = |w1.flat[o*I+i]| = |w1[row=o][col=i]|
                const float wv = fabsf(fast_tanh(wh[o * I_N + i]) *
                                       fast_sigmoid(mh[o * I_N + i]));
                const float xv = x[b * I_N + i];
                const float sg = (xv > 0.f) ? 1.f : ((xv < 0.f) ? -1.f : 0.f);
                p *= sg * wv + (1.0f - wv);
            }
            msv = fminf(fmaxf(p, -1.0f), 1.0f);
        }
        out[b * O_N + o] = g1 * ca[r] + omg * m1 * msv;
    }
}

extern "C" void kernel_launch(void* const* d_in, const int* in_sizes, int n_in,
                              void* d_out, int out_size, void* d_ws, size_t ws_size,
                              hipStream_t stream) {
    const float* x  = (const float*)d_in[0];   // [B, I]
    const float* wh = (const float*)d_in[1];   // [I, O]
    const float* mh = (const float*)d_in[2];   // [I, O]
    const float* g  = (const float*)d_in[3];   // [O]
    float* out = (float*)d_out;                // [B, O] fp32

    f16x8* bp = (f16x8*)d_ws;                  // 512 KB B frags (w1)

    prep_b_kernel<<<128, 256, 0, stream>>>(wh, mh, bp);
    nalu_main_kernel<<<dim3(16, 32), 256, 0, stream>>>(bp, x, g, wh, mh, out);
}